// Round 1
// baseline (5848.970 us; speedup 1.0000x reference)
//
#include <hip/hip_runtime.h>
#include <cstdint>
#include <cstddef>

// LaminarV1V2Network: B=1024, T=512, N=36, H=128, D_in=74.
// Persistent kernel: 256 blocks x 512 threads, 4 batch rows per block.
// Rows are independent -> no inter-block communication. All state in LDS.
// Round 0: fp32 everywhere (correctness baseline). GRU weights stream from L2.

#define NN   36
#define HH   128
#define DIN  74
#define KT   202   // DIN + HH
#define TT   512
#define RPB  4
#define NPAD 40

__device__ __forceinline__ float sigm(float x) { return 1.0f / (1.0f + expf(-x)); }

extern "C" __global__ void __launch_bounds__(512)
laminar_kernel(const float* __restrict__ packed,
               const float* __restrict__ Wl4,
               const float* __restrict__ Wl23,
               const float* __restrict__ Wsom,
               const float* __restrict__ Wz,
               const float* __restrict__ Wr,
               const float* __restrict__ Wh,
               const float* __restrict__ bz,
               const float* __restrict__ br,
               const float* __restrict__ bh,
               const float* __restrict__ Wq,
               const float* __restrict__ bq,
               const float* __restrict__ Wp,
               const float* __restrict__ bp,
               float* __restrict__ out)
{
    const int tid = threadIdx.x;
    const int r0  = blockIdx.x * RPB;

    // xh / rh / h stored as float4 over rows: [k].{x,y,z,w} = rows 0..3
    __shared__ __align__(16) float4 xh4[KT];
    __shared__ __align__(16) float4 rh4[HH];
    __shared__ __align__(16) float4 h4[HH];
    __shared__ float zLs[RPB][HH];
    __shared__ float zrp[4][2][RPB][HH];     // [kc][gate][row][f] partials (16 KB)
    __shared__ float hhp[8][RPB][HH];        // [kc8][row][f] partials  (16 KB)
    __shared__ __align__(16) float4 qpp[8][NPAD]; // q/pi partials [fc][o], rows in comps
    __shared__ float bzL[HH], brL[HH], bhL[HH];
    __shared__ float bqL[NN];
    __shared__ float bpS;
    __shared__ __align__(16) float l4s[2][RPB][NPAD];   // ping-pong state
    __shared__ __align__(16) float l23s[2][RPB][NPAD];
    __shared__ __align__(16) float soms[2][RPB][NPAD];
    __shared__ __align__(16) float adL[RPB][NPAD];      // in-place
    __shared__ __align__(16) float qlog[RPB][NPAD];
    __shared__ float pvL[RPB], qinvL[RPB], piL[RPB];

    // ---- init ----
    for (int i = tid; i < HH; i += 512) { bzL[i] = bz[i]; brL[i] = br[i]; bhL[i] = bh[i]; }
    if (tid < NN) bqL[tid] = bq[tid];
    if (tid == 0) bpS = bp[0];
    { float* z1 = (float*)l4s;  for (int i = tid; i < 2*RPB*NPAD; i += 512) z1[i] = 0.f; }
    { float* z2 = (float*)l23s; for (int i = tid; i < 2*RPB*NPAD; i += 512) z2[i] = 0.f; }
    { float* z3 = (float*)soms; for (int i = tid; i < 2*RPB*NPAD; i += 512) z3[i] = 0.f; }
    { float* z4 = (float*)adL;  for (int i = tid; i < RPB*NPAD;   i += 512) z4[i] = 0.f; }
    { float* z5 = (float*)h4;   for (int i = tid; i < HH*4;       i += 512) z5[i] = 0.f; }
    if (tid < RPB) pvL[tid] = 0.f;
    __syncthreads();

    const int f_   = tid & 127;       // P2/P4: feature
    const int rr_  = tid >> 7;        // P2/P4: row
    const int f2_  = tid & 63;        // P1/P3: feature pair (f = 2*f2_, 2*f2_+1)
    const int g_   = (tid >> 6) & 1;  // P1: gate (0=z, 1=r)
    const int kc_  = tid >> 7;        // P1: k-chunk 0..3
    const int kc8_ = tid >> 6;        // P3: k-chunk 0..7

    for (int t = 0; t < TT; ++t) {
        const int pp = t & 1;
        const int qq = 1 - pp;

        // ---- P0: xh = [r_l23_old(36), cue(36), task(2), h(128)] ----
        {
            const int rr = tid >> 7;
            const int kx = tid & 127;
            const size_t base = ((size_t)(r0 + rr) * TT + t) * DIN;
            float* xf = (float*)xh4;
            for (int k = kx; k < KT; k += 128) {
                float v;
                if (k < NN)       v = l23s[pp][rr][k];
                else if (k < DIN) v = packed[base + k];
                else              v = ((const float*)h4)[(k - DIN) * 4 + rr];
                xf[k * 4 + rr] = v;
            }
        }
        __syncthreads();

        // ---- P1: z,r gate partial matmuls (k-split 4, 2 feats/thread) ----
        {
            const float* __restrict__ Wg = g_ ? Wr : Wz;
            const int k0 = (kc_ * KT) >> 2;
            const int k1 = ((kc_ + 1) * KT) >> 2;
            float ax=0.f, ay=0.f, az=0.f, aw=0.f;
            float bx=0.f, by=0.f, bz2=0.f, bw=0.f;
            #pragma unroll 4
            for (int k = k0; k < k1; ++k) {
                const float2 w  = *(const float2*)&Wg[k * HH + 2 * f2_];
                const float4 xv = xh4[k];
                ax = fmaf(w.x, xv.x, ax);  bx  = fmaf(w.y, xv.x, bx);
                ay = fmaf(w.x, xv.y, ay);  by  = fmaf(w.y, xv.y, by);
                az = fmaf(w.x, xv.z, az);  bz2 = fmaf(w.y, xv.z, bz2);
                aw = fmaf(w.x, xv.w, aw);  bw  = fmaf(w.y, xv.w, bw);
            }
            *(float2*)&zrp[kc_][g_][0][2 * f2_] = make_float2(ax, bx);
            *(float2*)&zrp[kc_][g_][1][2 * f2_] = make_float2(ay, by);
            *(float2*)&zrp[kc_][g_][2][2 * f2_] = make_float2(az, bz2);
            *(float2*)&zrp[kc_][g_][3][2 * f2_] = make_float2(aw, bw);
        }
        __syncthreads();

        // ---- P2: sigmoid gates, r*h; L4 ring + adapt update (tid<144) ----
        {
            const float zraw = zrp[0][0][rr_][f_] + zrp[1][0][rr_][f_]
                             + zrp[2][0][rr_][f_] + zrp[3][0][rr_][f_] + bzL[f_];
            const float rraw = zrp[0][1][rr_][f_] + zrp[1][1][rr_][f_]
                             + zrp[2][1][rr_][f_] + zrp[3][1][rr_][f_] + brL[f_];
            const float zg = sigm(zraw);
            const float rg = sigm(rraw);
            zLs[rr_][f_] = zg;
            ((float*)rh4)[f_ * 4 + rr_] = rg * ((const float*)h4)[f_ * 4 + rr_];

            if (tid < 144) {
                const int r = tid / NN;
                const int i = tid - r * NN;
                float acc = packed[((size_t)(r0 + r) * TT + t) * DIN + i]
                          - pvL[r] - adL[r][i];                    // stim - W_PV*pv - adapt
                #pragma unroll
                for (int j = 0; j < NN; j += 4) {
                    const float4 rv = *(const float4*)&l4s[pp][r][j];
                    const float4 wv = *(const float4*)&Wl4[i * NN + j];
                    acc += rv.x*wv.x + rv.y*wv.y + rv.z*wv.z + rv.w*wv.w;
                }
                const float nl4 = 0.9f * l4s[pp][r][i] + 0.1f * fmaxf(acc, 0.f);
                l4s[qq][r][i] = nl4;
                adL[r][i] = 0.98f * adL[r][i] + 0.01f * nl4;
            }
        }
        __syncthreads();

        // ---- P3: hh partial matmuls over xrh = [x, r*h] (k-split 8) ----
        {
            const int k0 = (kc8_ * KT) >> 3;
            const int k1 = ((kc8_ + 1) * KT) >> 3;
            float ax=0.f, ay=0.f, az=0.f, aw=0.f;
            float bx=0.f, by=0.f, bz2=0.f, bw=0.f;
            const int kxe = k1 < DIN ? k1 : DIN;
            #pragma unroll 4
            for (int k = k0; k < kxe; ++k) {
                const float2 w  = *(const float2*)&Wh[k * HH + 2 * f2_];
                const float4 xv = xh4[k];
                ax = fmaf(w.x, xv.x, ax);  bx  = fmaf(w.y, xv.x, bx);
                ay = fmaf(w.x, xv.y, ay);  by  = fmaf(w.y, xv.y, by);
                az = fmaf(w.x, xv.z, az);  bz2 = fmaf(w.y, xv.z, bz2);
                aw = fmaf(w.x, xv.w, aw);  bw  = fmaf(w.y, xv.w, bw);
            }
            const int khs = k0 > DIN ? k0 : DIN;
            #pragma unroll 4
            for (int k = khs; k < k1; ++k) {
                const float2 w  = *(const float2*)&Wh[k * HH + 2 * f2_];
                const float4 xv = rh4[k - DIN];
                ax = fmaf(w.x, xv.x, ax);  bx  = fmaf(w.y, xv.x, bx);
                ay = fmaf(w.x, xv.y, ay);  by  = fmaf(w.y, xv.y, by);
                az = fmaf(w.x, xv.z, az);  bz2 = fmaf(w.y, xv.z, bz2);
                aw = fmaf(w.x, xv.w, aw);  bw  = fmaf(w.y, xv.w, bw);
            }
            *(float2*)&hhp[kc8_][0][2 * f2_] = make_float2(ax, bx);
            *(float2*)&hhp[kc8_][1][2 * f2_] = make_float2(ay, by);
            *(float2*)&hhp[kc8_][2][2 * f2_] = make_float2(az, bz2);
            *(float2*)&hhp[kc8_][3][2 * f2_] = make_float2(aw, bw);
        }
        __syncthreads();

        // ---- P4: h update; PV update (tid<4) ----
        {
            float hraw = bhL[f_];
            #pragma unroll
            for (int c = 0; c < 8; ++c) hraw += hhp[c][rr_][f_];
            const float hh = tanhf(hraw);
            const float zg = zLs[rr_][f_];
            float* hp = (float*)h4;
            const float hold = hp[f_ * 4 + rr_];
            hp[f_ * 4 + rr_] = (1.0f - zg) * hold + zg * hh;

            if (tid < RPB) {
                float s = 0.f;
                #pragma unroll
                for (int j = 0; j < NN; ++j) s += l4s[qq][tid][j] + l23s[pp][tid][j];
                const float pvin = s * (1.0f / 36.0f);
                pvL[tid] = 0.9f * pvL[tid] + 0.1f * fmaxf(pvin, 0.f);
            }
        }
        __syncthreads();

        // ---- P5: q/pi head partials: o = tid%37 (36=pi), fc = tid/37 ----
        if (tid < 296) {
            const int fc = tid / 37;
            const int o  = tid - fc * 37;
            const int f0 = fc * 16;
            float a0=0.f, a1=0.f, a2=0.f, a3=0.f;
            if (o < NN) {
                #pragma unroll 4
                for (int ff = f0; ff < f0 + 16; ++ff) {
                    const float  w  = Wq[ff * NN + o];
                    const float4 hv = h4[ff];
                    a0 = fmaf(w, hv.x, a0); a1 = fmaf(w, hv.y, a1);
                    a2 = fmaf(w, hv.z, a2); a3 = fmaf(w, hv.w, a3);
                }
            } else {
                #pragma unroll 4
                for (int ff = f0; ff < f0 + 16; ++ff) {
                    const float  w  = Wp[ff];
                    const float4 hv = h4[ff];
                    a0 = fmaf(w, hv.x, a0); a1 = fmaf(w, hv.y, a1);
                    a2 = fmaf(w, hv.z, a2); a3 = fmaf(w, hv.w, a3);
                }
            }
            qpp[fc][o] = make_float4(a0, a1, a2, a3);
        }
        __syncthreads();

        // ---- P5b: combine head partials (tid<148): o = tid%37, r = tid/37 ----
        if (tid < 148) {
            const int r = tid / 37;
            const int o = tid - r * 37;
            float s = 0.f;
            #pragma unroll
            for (int c = 0; c < 8; ++c) s += ((const float*)&qpp[c][o])[r];
            if (o < NN) qlog[r][o] = s + bqL[o];
            else        piL[r] = sigm(s + bpS);
        }
        __syncthreads();

        // ---- P6A: softmax per row, serial (tid<4) ----
        if (tid < RPB) {
            float m = -1e30f;
            for (int i = 0; i < NN; ++i) m = fmaxf(m, qlog[tid][i]);
            float ssum = 0.f;
            for (int i = 0; i < NN; ++i) {
                const float e = expf(qlog[tid][i] - m);
                qlog[tid][i] = e;
                ssum += e;
            }
            qinvL[tid] = 1.0f / ssum;
        }
        __syncthreads();

        // ---- P6d: SOM ring + L23 update + output (tid<144) ----
        if (tid < 144) {
            const int r = tid / NN;
            const int i = tid - r * NN;
            const float qp = qlog[r][i] * qinvL[r];
            const float dt = qp * piL[r];             // q_pred * pi_eff
            float acc = dt;                           // som_drive
            #pragma unroll
            for (int j = 0; j < NN; j += 4) {
                const float4 rv = *(const float4*)&soms[pp][r][j];
                const float4 wv = *(const float4*)&Wsom[i * NN + j];
                acc += rv.x*wv.x + rv.y*wv.y + rv.z*wv.z + rv.w*wv.w;
            }
            const float sn = 0.9f * soms[pp][r][i] + 0.1f * fmaxf(acc, 0.f);
            soms[qq][r][i] = sn;

            float acc2 = (l4s[qq][r][i] - dt) * (1.0f + 0.5f * dt) - 0.8f * sn - pvL[r];
            #pragma unroll
            for (int j = 0; j < NN; j += 4) {
                const float4 rv = *(const float4*)&l23s[pp][r][j];
                const float4 wv = *(const float4*)&Wl23[i * NN + j];
                acc2 += rv.x*wv.x + rv.y*wv.y + rv.z*wv.z + rv.w*wv.w;
            }
            const float ln = 0.9f * l23s[pp][r][i] + 0.1f * fmaxf(acc2, 0.f);
            l23s[qq][r][i] = ln;
            out[((size_t)(r0 + r) * TT + t) * NN + i] = ln;
        }
        __syncthreads();
    }
}

extern "C" void kernel_launch(void* const* d_in, const int* in_sizes, int n_in,
                              void* d_out, int out_size, void* d_ws, size_t ws_size,
                              hipStream_t stream) {
    (void)in_sizes; (void)n_in; (void)out_size; (void)d_ws; (void)ws_size;
    const float* packed = (const float*)d_in[0];
    const float* Wl4    = (const float*)d_in[1];
    const float* Wl23   = (const float*)d_in[2];
    const float* Wsom   = (const float*)d_in[3];
    const float* Wz     = (const float*)d_in[4];
    const float* Wr     = (const float*)d_in[5];
    const float* Wh     = (const float*)d_in[6];
    const float* bz     = (const float*)d_in[7];
    const float* br     = (const float*)d_in[8];
    const float* bh     = (const float*)d_in[9];
    const float* Wq     = (const float*)d_in[10];
    const float* bq     = (const float*)d_in[11];
    const float* Wp     = (const float*)d_in[12];
    const float* bp     = (const float*)d_in[13];
    // d_in[14] (Ws), d_in[15] (bs): dead code in the reference output path.
    float* out = (float*)d_out;

    laminar_kernel<<<256, 512, 0, stream>>>(packed, Wl4, Wl23, Wsom,
                                            Wz, Wr, Wh, bz, br, bh,
                                            Wq, bq, Wp, bp, out);
}

// Round 2
// 2706.891 us; speedup vs baseline: 2.1608x; 2.1608x over previous
//
#include <hip/hip_runtime.h>
#include <cstdint>
#include <cstddef>

// LaminarV1V2Network: B=1024, T=512, N=36, H=128, D_in=74, K=202.
// R1: GRU + heads via bf16 MFMA (16x16x32). Weights bf16 (pre-swizzled into
// d_ws fragments by init kernel each launch); activations split-bf16 hi+lo
// (2 MFMAs per B-fragment) => fp32-class activation accuracy.
// 256 blocks x 512 threads, 4 rows/block, state in LDS. Rings/heads fp32 VALU.

#define NN   36
#define HH   128
#define DIN  74
#define KT   202
#define KP   224      // K padded to 7 slabs of 32
#define TT   512
#define RPB  4
#define NPAD 40

typedef short bf16x8 __attribute__((ext_vector_type(8)));
typedef float f32x4  __attribute__((ext_vector_type(4)));

#define MFMA(a,b,c) __builtin_amdgcn_mfma_f32_16x16x32_bf16((a),(b),(c),0,0,0)

__device__ __forceinline__ float sigm(float x) { return 1.0f / (1.0f + expf(-x)); }

__device__ __forceinline__ short f2bf(float v) {
    union { float f; unsigned u; } x; x.f = v;
    unsigned r = (x.u + 0x7fffu + ((x.u >> 16) & 1u)) >> 16;   // RNE
    return (short)r;
}
__device__ __forceinline__ float bf2f(short s) {
    union { unsigned u; float f; } y; y.u = ((unsigned)(unsigned short)s) << 16;
    return y.f;
}

// ---- fragment layout in ws (shorts) ----
// GRU tiles T = m*8+nt (m: 0=Wz,1=Wr,2=Wh; nt: 16-feature tile), 7 slabs:
//   off = T*7*512 + s*512 + lane*8 + j ;  k = s*32 + (lane>>4)*8 + j, n = nt*16 + (lane&15)
// HEAD tiles t in [0,3), 4 slabs, base 86016:
//   off = 86016 + (t*4+s)*512 + lane*8 + j ; cols: <36 Wq, ==36 Wp, else 0
#define HEADBASE 86016
#define FRAG_TOTAL 92160

extern "C" __global__ void __launch_bounds__(256)
init_frags(const float* __restrict__ Wz, const float* __restrict__ Wr,
           const float* __restrict__ Wh, const float* __restrict__ Wq,
           const float* __restrict__ Wp, short* __restrict__ frag)
{
    int idx = blockIdx.x * 256 + threadIdx.x;
    if (idx >= FRAG_TOTAL) return;
    float v;
    if (idx < HEADBASE) {
        int T = idx / 3584; int rem = idx - T * 3584;
        int s = rem >> 9;   int e = rem & 511;
        int l = e >> 3, j = e & 7;
        int k = s * 32 + ((l >> 4) << 3) + j;
        int n = ((T & 7) << 4) + (l & 15);
        const float* W = (T < 8) ? Wz : (T < 16) ? Wr : Wh;
        v = (k < KT) ? W[k * HH + n] : 0.f;
    } else {
        int r2 = idx - HEADBASE;
        int ts = r2 >> 9; int e = r2 & 511;
        int t = ts >> 2, s = ts & 3;
        int l = e >> 3, j = e & 7;
        int k = s * 32 + ((l >> 4) << 3) + j;     // < 128
        int c = (t << 4) + (l & 15);
        v = (c < NN) ? Wq[k * NN + c] : (c == NN ? Wp[k] : 0.f);
    }
    frag[idx] = f2bf(v);
}

extern "C" __global__ void __launch_bounds__(512)
laminar_kernel(const float* __restrict__ packed,
               const float* __restrict__ Wl4,
               const float* __restrict__ Wl23,
               const float* __restrict__ Wsom,
               const float* __restrict__ bz,
               const float* __restrict__ br,
               const float* __restrict__ bh,
               const float* __restrict__ bq,
               const float* __restrict__ bp,
               const short* __restrict__ frag,
               float* __restrict__ out)
{
    const int tid  = threadIdx.x;
    const int r0   = blockIdx.x * RPB;
    const int lane = tid & 63;
    const int w    = tid >> 6;
    const int m    = lane & 15;
    const int q    = lane >> 4;

    __shared__ __align__(16) short xa_hi[RPB][KP], xa_lo[RPB][KP];  // z/r A: [x, h]
    __shared__ __align__(16) short xb_hi[RPB][KP], xb_lo[RPB][KP];  // hh  A: [x, r*h]
    __shared__ __align__(16) short hb_hi[RPB][HH], hb_lo[RPB][HH];  // head A: h_new
    __shared__ float hS[RPB][HH];
    __shared__ float zgS[RPB][HH];
    __shared__ float zr_pre[2][RPB][HH];
    __shared__ float hh_pre[RPB][HH];
    __shared__ float preq[RPB][48];
    __shared__ float dts[RPB][NPAD];
    __shared__ __align__(16) float l4s[2][RPB][NPAD];
    __shared__ __align__(16) float l23s[2][RPB][NPAD];
    __shared__ __align__(16) float soms[2][RPB][NPAD];
    __shared__ __align__(16) float adL[RPB][NPAD];
    __shared__ float bzL[HH], brL[HH], bhL[HH], bqL[48];
    __shared__ float pvL[RPB];
    __shared__ float bpS;

    // ---- one-time init ----
    for (int i = tid; i < HH; i += 512) { bzL[i] = bz[i]; brL[i] = br[i]; bhL[i] = bh[i]; }
    for (int i = tid; i < 48; i += 512) bqL[i] = (i < NN) ? bq[i] : 0.f;
    if (tid == 0) bpS = bp[0];
    { short* p = (short*)xa_hi; for (int i = tid; i < RPB*KP; i += 512) p[i] = 0; }
    { short* p = (short*)xa_lo; for (int i = tid; i < RPB*KP; i += 512) p[i] = 0; }
    { short* p = (short*)xb_hi; for (int i = tid; i < RPB*KP; i += 512) p[i] = 0; }
    { short* p = (short*)xb_lo; for (int i = tid; i < RPB*KP; i += 512) p[i] = 0; }
    { short* p = (short*)hb_hi; for (int i = tid; i < RPB*HH; i += 512) p[i] = 0; }
    { short* p = (short*)hb_lo; for (int i = tid; i < RPB*HH; i += 512) p[i] = 0; }
    { float* p = (float*)hS;    for (int i = tid; i < RPB*HH; i += 512) p[i] = 0.f; }
    { float* p = (float*)l4s;   for (int i = tid; i < 2*RPB*NPAD; i += 512) p[i] = 0.f; }
    { float* p = (float*)l23s;  for (int i = tid; i < 2*RPB*NPAD; i += 512) p[i] = 0.f; }
    { float* p = (float*)soms;  for (int i = tid; i < 2*RPB*NPAD; i += 512) p[i] = 0.f; }
    { float* p = (float*)adL;   for (int i = tid; i < RPB*NPAD;   i += 512) p[i] = 0.f; }
    if (tid < RPB) pvL[tid] = 0.f;
    __syncthreads();

    for (int t = 0; t < TT; ++t) {
        const int pp = t & 1;
        const int qq = 1 - pp;

        // ---- P0: x-part (k<74) of A buffers, split bf16 hi/lo ----
        if (tid < 296) {
            const int r = tid / DIN;
            const int k = tid - r * DIN;
            const float v = (k < NN) ? l23s[pp][r][k]
                                     : packed[((size_t)(r0 + r) * TT + t) * DIN + k];
            const short hi = f2bf(v);
            const short lo = f2bf(v - bf2f(hi));
            xa_hi[r][k] = hi; xa_lo[r][k] = lo;
            if (k >= 64) { xb_hi[r][k] = hi; xb_lo[r][k] = lo; }
        }
        __syncthreads();

        // ---- P1: z,r via MFMA. wave w: gate g=w&1, tiles nt0, nt0+4 ----
        bf16x8 Ahi[7], Alo[7];
        {
            if (m < RPB) {
                #pragma unroll
                for (int s = 0; s < 7; ++s) {
                    Ahi[s] = *(const bf16x8*)&xa_hi[m][s * 32 + q * 8];
                    Alo[s] = *(const bf16x8*)&xa_lo[m][s * 32 + q * 8];
                }
            } else {
                const bf16x8 zz = {0,0,0,0,0,0,0,0};
                #pragma unroll
                for (int s = 0; s < 7; ++s) { Ahi[s] = zz; Alo[s] = zz; }
            }
            const int g   = w & 1;
            const int nt0 = w >> 1;
            const short* bp0 = frag + ((g * 8 + nt0) * 7) * 512 + lane * 8;
            const short* bp1 = frag + ((g * 8 + nt0 + 4) * 7) * 512 + lane * 8;
            f32x4 acc0 = {0.f,0.f,0.f,0.f}, acc1 = {0.f,0.f,0.f,0.f};
            #pragma unroll
            for (int s = 0; s < 7; ++s) {
                const bf16x8 b0 = *(const bf16x8*)(bp0 + s * 512);
                const bf16x8 b1 = *(const bf16x8*)(bp1 + s * 512);
                acc0 = MFMA(Ahi[s], b0, acc0);
                acc1 = MFMA(Ahi[s], b1, acc1);
                acc0 = MFMA(Alo[s], b0, acc0);
                acc1 = MFMA(Alo[s], b1, acc1);
            }
            if (lane < 16) {
                #pragma unroll
                for (int e = 0; e < 4; ++e) {
                    zr_pre[g][e][nt0 * 16 + lane]       = acc0[e];
                    zr_pre[g][e][(nt0 + 4) * 16 + lane] = acc1[e];
                }
            }
        }
        __syncthreads();

        // ---- P2: gates; r*h -> xb (bf16 hi/lo); L4 ring + adapt (tid<144) ----
        {
            const int f  = tid & 127;
            const int rr = tid >> 7;
            const float zg = sigm(zr_pre[0][rr][f] + bzL[f]);
            const float rg = sigm(zr_pre[1][rr][f] + brL[f]);
            zgS[rr][f] = zg;
            const float rhv = rg * hS[rr][f];
            const short hi = f2bf(rhv);
            const short lo = f2bf(rhv - bf2f(hi));
            xb_hi[rr][DIN + f] = hi; xb_lo[rr][DIN + f] = lo;

            if (tid < 144) {
                const int r = tid / NN;
                const int i = tid - r * NN;
                float acc = packed[((size_t)(r0 + r) * TT + t) * DIN + i]
                          - pvL[r] - adL[r][i];
                #pragma unroll
                for (int j = 0; j < NN; j += 4) {
                    const float4 rv = *(const float4*)&l4s[pp][r][j];
                    const float4 wv = *(const float4*)&Wl4[i * NN + j];
                    acc += rv.x*wv.x + rv.y*wv.y + rv.z*wv.z + rv.w*wv.w;
                }
                const float nl4 = 0.9f * l4s[pp][r][i] + 0.1f * fmaxf(acc, 0.f);
                l4s[qq][r][i] = nl4;
                adL[r][i] = 0.98f * adL[r][i] + 0.01f * nl4;
            }
        }
        __syncthreads();

        // ---- P3: hh via MFMA. wave w -> tile w. slabs 0-1 reuse Ahi/Alo ----
        {
            bf16x8 Bhi[5], Blo[5];
            if (m < RPB) {
                #pragma unroll
                for (int s = 0; s < 5; ++s) {
                    Bhi[s] = *(const bf16x8*)&xb_hi[m][(s + 2) * 32 + q * 8];
                    Blo[s] = *(const bf16x8*)&xb_lo[m][(s + 2) * 32 + q * 8];
                }
            } else {
                const bf16x8 zz = {0,0,0,0,0,0,0,0};
                #pragma unroll
                for (int s = 0; s < 5; ++s) { Bhi[s] = zz; Blo[s] = zz; }
            }
            const short* bph = frag + ((16 + w) * 7) * 512 + lane * 8;
            f32x4 acc = {0.f,0.f,0.f,0.f};
            #pragma unroll
            for (int s = 0; s < 2; ++s) {
                const bf16x8 b = *(const bf16x8*)(bph + s * 512);
                acc = MFMA(Ahi[s], b, acc);
                acc = MFMA(Alo[s], b, acc);
            }
            #pragma unroll
            for (int s = 2; s < 7; ++s) {
                const bf16x8 b = *(const bf16x8*)(bph + s * 512);
                acc = MFMA(Bhi[s - 2], b, acc);
                acc = MFMA(Blo[s - 2], b, acc);
            }
            if (lane < 16) {
                #pragma unroll
                for (int e = 0; e < 4; ++e) hh_pre[e][w * 16 + lane] = acc[e];
            }
        }
        __syncthreads();

        // ---- P4: h update; write h bf16 into hb (heads) and xa (next step) ----
        {
            const int f  = tid & 127;
            const int rr = tid >> 7;
            const float hhv = tanhf(hh_pre[rr][f] + bhL[f]);
            const float zg  = zgS[rr][f];
            const float hn  = (1.0f - zg) * hS[rr][f] + zg * hhv;
            hS[rr][f] = hn;
            const short hi = f2bf(hn);
            const short lo = f2bf(hn - bf2f(hi));
            hb_hi[rr][f] = hi;       hb_lo[rr][f] = lo;
            xa_hi[rr][DIN + f] = hi; xa_lo[rr][DIN + f] = lo;
        }
        __syncthreads();

        // ---- P5: heads via MFMA (waves 0-2); PV update (wave 3) ----
        {
            if (w < 3) {
                bf16x8 Hhi[4], Hlo[4];
                if (m < RPB) {
                    #pragma unroll
                    for (int s = 0; s < 4; ++s) {
                        Hhi[s] = *(const bf16x8*)&hb_hi[m][s * 32 + q * 8];
                        Hlo[s] = *(const bf16x8*)&hb_lo[m][s * 32 + q * 8];
                    }
                } else {
                    const bf16x8 zz = {0,0,0,0,0,0,0,0};
                    #pragma unroll
                    for (int s = 0; s < 4; ++s) { Hhi[s] = zz; Hlo[s] = zz; }
                }
                const short* bp2 = frag + HEADBASE + (w * 4) * 512 + lane * 8;
                f32x4 acc = {0.f,0.f,0.f,0.f};
                #pragma unroll
                for (int s = 0; s < 4; ++s) {
                    const bf16x8 b = *(const bf16x8*)(bp2 + s * 512);
                    acc = MFMA(Hhi[s], b, acc);
                    acc = MFMA(Hlo[s], b, acc);
                }
                if (lane < 16) {
                    #pragma unroll
                    for (int e = 0; e < 4; ++e) preq[e][w * 16 + lane] = acc[e];
                }
            } else if (w == 3 && lane < RPB) {
                float s = 0.f;
                #pragma unroll
                for (int j = 0; j < NN; ++j) s += l4s[qq][lane][j] + l23s[pp][lane][j];
                pvL[lane] = 0.9f * pvL[lane] + 0.1f * fmaxf(s * (1.0f / 36.0f), 0.f);
            }
        }
        __syncthreads();

        // ---- P6A: wave-parallel softmax + pi -> dts = q_pred * pi ----
        if (tid < 256) {
            const int rr = tid >> 6;
            float v = (lane < 48) ? preq[rr][lane] : -1e30f;
            if (lane < 36)       v += bqL[lane];
            else if (lane == 36) v += bpS;
            float sv = (lane < NN) ? v : -1e30f;
            #pragma unroll
            for (int d = 32; d >= 1; d >>= 1) sv = fmaxf(sv, __shfl_xor(sv, d));
            const float e = (lane < NN) ? expf(v - sv) : 0.f;
            float ss = e;
            #pragma unroll
            for (int d = 32; d >= 1; d >>= 1) ss += __shfl_xor(ss, d);
            const float pi = sigm(__shfl(v, 36));
            if (lane < NN) dts[rr][lane] = (e / ss) * pi;
        }
        __syncthreads();

        // ---- P6d: SOM ring + L23 update + output (tid<144) ----
        if (tid < 144) {
            const int r = tid / NN;
            const int i = tid - r * NN;
            const float dt = dts[r][i];
            float acc = dt;
            #pragma unroll
            for (int j = 0; j < NN; j += 4) {
                const float4 rv = *(const float4*)&soms[pp][r][j];
                const float4 wv = *(const float4*)&Wsom[i * NN + j];
                acc += rv.x*wv.x + rv.y*wv.y + rv.z*wv.z + rv.w*wv.w;
            }
            const float sn = 0.9f * soms[pp][r][i] + 0.1f * fmaxf(acc, 0.f);
            soms[qq][r][i] = sn;

            float acc2 = (l4s[qq][r][i] - dt) * (1.0f + 0.5f * dt) - 0.8f * sn - pvL[r];
            #pragma unroll
            for (int j = 0; j < NN; j += 4) {
                const float4 rv = *(const float4*)&l23s[pp][r][j];
                const float4 wv = *(const float4*)&Wl23[i * NN + j];
                acc2 += rv.x*wv.x + rv.y*wv.y + rv.z*wv.z + rv.w*wv.w;
            }
            const float ln = 0.9f * l23s[pp][r][i] + 0.1f * fmaxf(acc2, 0.f);
            l23s[qq][r][i] = ln;
            out[((size_t)(r0 + r) * TT + t) * NN + i] = ln;
        }
        __syncthreads();
    }
}

extern "C" void kernel_launch(void* const* d_in, const int* in_sizes, int n_in,
                              void* d_out, int out_size, void* d_ws, size_t ws_size,
                              hipStream_t stream) {
    (void)in_sizes; (void)n_in; (void)out_size; (void)ws_size;
    const float* packed = (const float*)d_in[0];
    const float* Wl4    = (const float*)d_in[1];
    const float* Wl23   = (const float*)d_in[2];
    const float* Wsom   = (const float*)d_in[3];
    const float* Wz     = (const float*)d_in[4];
    const float* Wr     = (const float*)d_in[5];
    const float* Wh     = (const float*)d_in[6];
    const float* bz     = (const float*)d_in[7];
    const float* br     = (const float*)d_in[8];
    const float* bh     = (const float*)d_in[9];
    const float* Wq     = (const float*)d_in[10];
    const float* bq     = (const float*)d_in[11];
    const float* Wp     = (const float*)d_in[12];
    const float* bp     = (const float*)d_in[13];
    float* out  = (float*)d_out;
    short* frag = (short*)d_ws;   // needs 184320 B

    init_frags<<<(FRAG_TOTAL + 255) / 256, 256, 0, stream>>>(Wz, Wr, Wh, Wq, Wp, frag);
    laminar_kernel<<<256, 512, 0, stream>>>(packed, Wl4, Wl23, Wsom,
                                            bz, br, bh, bq, bp, frag, out);
}

// Round 3
// 2392.271 us; speedup vs baseline: 2.4449x; 1.1315x over previous
//
#include <hip/hip_runtime.h>
#include <cstdint>
#include <cstddef>

// LaminarV1V2Network: B=1024, T=512, N=36, H=128, D_in=74, K=202.
// R2: register-resident bf16 weight fragments (loaded once, ~100 VGPR/wave),
// lgkm-only barriers (no vmcnt drain), input prefetch pipelined one step
// ahead, 6 phases/step. Activations split-bf16 hi+lo (2 MFMAs per B-frag).
// 256 blocks x 512 threads, 4 rows/block, state in LDS.

#define NN   36
#define HH   128
#define DIN  74
#define KT   202
#define KP   224      // K padded to 7 slabs of 32
#define TT   512
#define RPB  4
#define NPAD 40

typedef short bf16x8 __attribute__((ext_vector_type(8)));
typedef float f32x4  __attribute__((ext_vector_type(4)));

#define MFMA(a,b,c) __builtin_amdgcn_mfma_f32_16x16x32_bf16((a),(b),(c),0,0,0)
// Barrier that orders LDS only: global loads/stores float across it.
#define BAR() asm volatile("s_waitcnt lgkmcnt(0)\n\ts_barrier" ::: "memory")

__device__ __forceinline__ float sigm(float x) { return 1.0f / (1.0f + expf(-x)); }

__device__ __forceinline__ short f2bf(float v) {
    union { float f; unsigned u; } x; x.f = v;
    unsigned r = (x.u + 0x7fffu + ((x.u >> 16) & 1u)) >> 16;   // RNE
    return (short)r;
}
__device__ __forceinline__ float bf2f(short s) {
    union { unsigned u; float f; } y; y.u = ((unsigned)(unsigned short)s) << 16;
    return y.f;
}

// ---- fragment layout in ws (shorts) ----
// GRU tiles T = m*8+nt (m: 0=Wz,1=Wr,2=Wh; nt: 16-feature tile), 7 slabs:
//   off = T*7*512 + s*512 + lane*8 + j ;  k = s*32 + (lane>>4)*8 + j, n = nt*16 + (lane&15)
// HEAD tiles t in [0,3), 4 slabs, base 86016:
//   off = 86016 + (t*4+s)*512 + lane*8 + j ; cols: <36 Wq, ==36 Wp, else 0
#define HEADBASE 86016
#define FRAG_TOTAL 92160

extern "C" __global__ void __launch_bounds__(256)
init_frags(const float* __restrict__ Wz, const float* __restrict__ Wr,
           const float* __restrict__ Wh, const float* __restrict__ Wq,
           const float* __restrict__ Wp, short* __restrict__ frag)
{
    int idx = blockIdx.x * 256 + threadIdx.x;
    if (idx >= FRAG_TOTAL) return;
    float v;
    if (idx < HEADBASE) {
        int T = idx / 3584; int rem = idx - T * 3584;
        int s = rem >> 9;   int e = rem & 511;
        int l = e >> 3, j = e & 7;
        int k = s * 32 + ((l >> 4) << 3) + j;
        int n = ((T & 7) << 4) + (l & 15);
        const float* W = (T < 8) ? Wz : (T < 16) ? Wr : Wh;
        v = (k < KT) ? W[k * HH + n] : 0.f;
    } else {
        int r2 = idx - HEADBASE;
        int ts = r2 >> 9; int e = r2 & 511;
        int t = ts >> 2, s = ts & 3;
        int l = e >> 3, j = e & 7;
        int k = s * 32 + ((l >> 4) << 3) + j;     // < 128
        int c = (t << 4) + (l & 15);
        v = (c < NN) ? Wq[k * NN + c] : (c == NN ? Wp[k] : 0.f);
    }
    frag[idx] = f2bf(v);
}

extern "C" __global__ void __launch_bounds__(512, 2)
laminar_kernel(const float* __restrict__ packed,
               const float* __restrict__ Wl4,
               const float* __restrict__ Wl23,
               const float* __restrict__ Wsom,
               const float* __restrict__ bz,
               const float* __restrict__ br,
               const float* __restrict__ bh,
               const float* __restrict__ bq,
               const float* __restrict__ bp,
               const short* __restrict__ frag,
               float* __restrict__ out)
{
    const int tid  = threadIdx.x;
    const int r0   = blockIdx.x * RPB;
    const int lane = tid & 63;
    const int w    = tid >> 6;
    const int m    = lane & 15;
    const int q    = lane >> 4;

    __shared__ __align__(16) short xa_hi[RPB][KP], xa_lo[RPB][KP];  // z/r A: [x, h]
    __shared__ __align__(16) short xb_hi[RPB][KP], xb_lo[RPB][KP];  // hh  A: [x, r*h]
    __shared__ __align__(16) short hb_hi[RPB][HH], hb_lo[RPB][HH];  // head A: h_new
    __shared__ float hS[RPB][HH];
    __shared__ float zgS[RPB][HH];
    __shared__ float zr_pre[2][HH][5];     // [gate][feature][row], stride-5: conflict-free
    __shared__ float hh_pre[HH][5];
    __shared__ float preq[48][5];
    __shared__ __align__(16) float l4s[2][RPB][NPAD];
    __shared__ __align__(16) float l23s[2][RPB][NPAD];
    __shared__ __align__(16) float soms[2][RPB][NPAD];
    __shared__ __align__(16) float adL[RPB][NPAD];
    __shared__ float bzL[HH], brL[HH], bhL[HH], bqL[48];
    __shared__ float pvL[RPB];
    __shared__ float bpS;

    // ---- one-time init ----
    for (int i = tid; i < HH; i += 512) { bzL[i] = bz[i]; brL[i] = br[i]; bhL[i] = bh[i]; }
    for (int i = tid; i < 48; i += 512) bqL[i] = (i < NN) ? bq[i] : 0.f;
    if (tid == 0) bpS = bp[0];
    { short* p = (short*)xa_hi; for (int i = tid; i < RPB*KP; i += 512) p[i] = 0; }
    { short* p = (short*)xa_lo; for (int i = tid; i < RPB*KP; i += 512) p[i] = 0; }
    { short* p = (short*)xb_hi; for (int i = tid; i < RPB*KP; i += 512) p[i] = 0; }
    { short* p = (short*)xb_lo; for (int i = tid; i < RPB*KP; i += 512) p[i] = 0; }
    { short* p = (short*)hb_hi; for (int i = tid; i < RPB*HH; i += 512) p[i] = 0; }
    { short* p = (short*)hb_lo; for (int i = tid; i < RPB*HH; i += 512) p[i] = 0; }
    { float* p = (float*)hS;    for (int i = tid; i < RPB*HH; i += 512) p[i] = 0.f; }
    { float* p = (float*)l4s;   for (int i = tid; i < 2*RPB*NPAD; i += 512) p[i] = 0.f; }
    { float* p = (float*)l23s;  for (int i = tid; i < 2*RPB*NPAD; i += 512) p[i] = 0.f; }
    { float* p = (float*)soms;  for (int i = tid; i < 2*RPB*NPAD; i += 512) p[i] = 0.f; }
    { float* p = (float*)adL;   for (int i = tid; i < RPB*NPAD;   i += 512) p[i] = 0.f; }
    if (tid < RPB) pvL[tid] = 0.f;

    // ---- persistent weight fragments in VGPRs ----
    const int g   = w & 1;       // P1 gate (0=z, 1=r)
    const int nt0 = w >> 1;      // P1 first tile
    bf16x8 Wg0[7], Wg1[7], WhR[7], WhdR[4];
    {
        const short* b0 = frag + ((g * 8 + nt0) * 7) * 512 + lane * 8;
        const short* b1 = frag + ((g * 8 + nt0 + 4) * 7) * 512 + lane * 8;
        #pragma unroll
        for (int s = 0; s < 7; ++s) {
            Wg0[s] = *(const bf16x8*)(b0 + s * 512);
            Wg1[s] = *(const bf16x8*)(b1 + s * 512);
        }
        const short* b2 = frag + ((16 + w) * 7) * 512 + lane * 8;
        #pragma unroll
        for (int s = 0; s < 7; ++s) WhR[s] = *(const bf16x8*)(b2 + s * 512);
        const int hw = (w < 3) ? w : 0;
        const short* b3 = frag + HEADBASE + (hw * 4) * 512 + lane * 8;
        #pragma unroll
        for (int s = 0; s < 4; ++s) WhdR[s] = *(const bf16x8*)(b3 + s * 512);
    }

    // ---- input prefetch prologue ----
    float stim_pf = 0.f; int sr = 0, si = 0;
    if (tid < 144) {
        sr = tid / NN; si = tid - sr * NN;
        stim_pf = packed[((size_t)(r0 + sr) * TT + 0) * DIN + si];
    }
    float ct_pf = 0.f; int cr = 0, ck = 0;
    if (tid >= 256 && tid < 408) {
        cr = (tid - 256) / 38; ck = 36 + (tid - 256) % 38;
        const float v0 = packed[((size_t)(r0 + cr) * TT + 0) * DIN + ck];
        const short hi = f2bf(v0);
        const short lo = f2bf(v0 - bf2f(hi));
        xa_hi[cr][ck] = hi; xa_lo[cr][ck] = lo;
        if (ck >= 64) { xb_hi[cr][ck] = hi; xb_lo[cr][ck] = lo; }
        ct_pf = packed[((size_t)(r0 + cr) * TT + 1) * DIN + ck];
    }
    __syncthreads();

    for (int t = 0; t < TT; ++t) {
        const int pp = t & 1;
        const int qq = 1 - pp;

        // ---- P1: z,r via MFMA (register weights) ----
        bf16x8 Ahi[7], Alo[7];
        {
            if (m < RPB) {
                #pragma unroll
                for (int s = 0; s < 7; ++s) {
                    Ahi[s] = *(const bf16x8*)&xa_hi[m][s * 32 + q * 8];
                    Alo[s] = *(const bf16x8*)&xa_lo[m][s * 32 + q * 8];
                }
            } else {
                const bf16x8 zz = {0,0,0,0,0,0,0,0};
                #pragma unroll
                for (int s = 0; s < 7; ++s) { Ahi[s] = zz; Alo[s] = zz; }
            }
            f32x4 a0h = {0.f,0.f,0.f,0.f}, a0l = {0.f,0.f,0.f,0.f};
            f32x4 a1h = {0.f,0.f,0.f,0.f}, a1l = {0.f,0.f,0.f,0.f};
            #pragma unroll
            for (int s = 0; s < 7; ++s) {
                a0h = MFMA(Ahi[s], Wg0[s], a0h);
                a1h = MFMA(Ahi[s], Wg1[s], a1h);
                a0l = MFMA(Alo[s], Wg0[s], a0l);
                a1l = MFMA(Alo[s], Wg1[s], a1l);
            }
            if (lane < 16) {
                #pragma unroll
                for (int e = 0; e < 4; ++e) {
                    zr_pre[g][nt0 * 16 + lane][e]       = a0h[e] + a0l[e];
                    zr_pre[g][(nt0 + 4) * 16 + lane][e] = a1h[e] + a1l[e];
                }
            }
        }
        BAR();

        // ---- P2: gates; r*h -> xb; L4 ring + adapt (tid<144) ----
        {
            const int f  = tid & 127;
            const int rr = tid >> 7;
            const float zg = sigm(zr_pre[0][f][rr] + bzL[f]);
            const float rg = sigm(zr_pre[1][f][rr] + brL[f]);
            zgS[rr][f] = zg;
            const float rhv = rg * hS[rr][f];
            const short hi = f2bf(rhv);
            const short lo = f2bf(rhv - bf2f(hi));
            xb_hi[rr][DIN + f] = hi; xb_lo[rr][DIN + f] = lo;

            if (tid < 144) {
                float acc = stim_pf - pvL[sr] - adL[sr][si];
                #pragma unroll
                for (int j = 0; j < NN; j += 4) {
                    const float4 rv = *(const float4*)&l4s[pp][sr][j];
                    const float4 wv = *(const float4*)&Wl4[si * NN + j];
                    acc += rv.x*wv.x + rv.y*wv.y + rv.z*wv.z + rv.w*wv.w;
                }
                const float nl4 = 0.9f * l4s[pp][sr][si] + 0.1f * fmaxf(acc, 0.f);
                l4s[qq][sr][si] = nl4;
                adL[sr][si] = 0.98f * adL[sr][si] + 0.01f * nl4;
                const int tn = (t + 1 < TT) ? t + 1 : t;
                stim_pf = packed[((size_t)(r0 + sr) * TT + tn) * DIN + si];
            }
        }
        BAR();

        // ---- P3: hh via MFMA; slabs 0-1 reuse Ahi/Alo ----
        {
            bf16x8 Bhi[5], Blo[5];
            if (m < RPB) {
                #pragma unroll
                for (int s = 0; s < 5; ++s) {
                    Bhi[s] = *(const bf16x8*)&xb_hi[m][(s + 2) * 32 + q * 8];
                    Blo[s] = *(const bf16x8*)&xb_lo[m][(s + 2) * 32 + q * 8];
                }
            } else {
                const bf16x8 zz = {0,0,0,0,0,0,0,0};
                #pragma unroll
                for (int s = 0; s < 5; ++s) { Bhi[s] = zz; Blo[s] = zz; }
            }
            f32x4 ah = {0.f,0.f,0.f,0.f}, al = {0.f,0.f,0.f,0.f};
            #pragma unroll
            for (int s = 0; s < 2; ++s) {
                ah = MFMA(Ahi[s], WhR[s], ah);
                al = MFMA(Alo[s], WhR[s], al);
            }
            #pragma unroll
            for (int s = 2; s < 7; ++s) {
                ah = MFMA(Bhi[s - 2], WhR[s], ah);
                al = MFMA(Blo[s - 2], WhR[s], al);
            }
            if (lane < 16) {
                #pragma unroll
                for (int e = 0; e < 4; ++e) hh_pre[w * 16 + lane][e] = ah[e] + al[e];
            }
        }
        BAR();

        // ---- P4: h update; write h bf16 into hb (heads) and xa (next step) ----
        {
            const int f  = tid & 127;
            const int rr = tid >> 7;
            const float hhv = tanhf(hh_pre[f][rr] + bhL[f]);
            const float zg  = zgS[rr][f];
            const float hn  = (1.0f - zg) * hS[rr][f] + zg * hhv;
            hS[rr][f] = hn;
            const short hi = f2bf(hn);
            const short lo = f2bf(hn - bf2f(hi));
            hb_hi[rr][f] = hi;       hb_lo[rr][f] = lo;
            xa_hi[rr][DIN + f] = hi; xa_lo[rr][DIN + f] = lo;
        }
        BAR();

        // ---- P5: heads MFMA (w<3) | PV (w==3) | cue/task store+prefetch (w>=4) ----
        if (w < 3) {
            bf16x8 Hhi[4], Hlo[4];
            if (m < RPB) {
                #pragma unroll
                for (int s = 0; s < 4; ++s) {
                    Hhi[s] = *(const bf16x8*)&hb_hi[m][s * 32 + q * 8];
                    Hlo[s] = *(const bf16x8*)&hb_lo[m][s * 32 + q * 8];
                }
            } else {
                const bf16x8 zz = {0,0,0,0,0,0,0,0};
                #pragma unroll
                for (int s = 0; s < 4; ++s) { Hhi[s] = zz; Hlo[s] = zz; }
            }
            f32x4 ah = {0.f,0.f,0.f,0.f}, al = {0.f,0.f,0.f,0.f};
            #pragma unroll
            for (int s = 0; s < 4; ++s) {
                ah = MFMA(Hhi[s], WhdR[s], ah);
                al = MFMA(Hlo[s], WhdR[s], al);
            }
            if (lane < 16) {
                #pragma unroll
                for (int e = 0; e < 4; ++e) preq[w * 16 + lane][e] = ah[e] + al[e];
            }
        } else if (w == 3) {
            const int row = lane >> 4;
            const int jj  = lane & 15;
            float s = 0.f;
            for (int j = jj; j < NN; j += 16) s += l4s[qq][row][j] + l23s[pp][row][j];
            s += __shfl_xor(s, 8); s += __shfl_xor(s, 4);
            s += __shfl_xor(s, 2); s += __shfl_xor(s, 1);
            if (jj == 0) pvL[row] = 0.9f * pvL[row] + 0.1f * fmaxf(s * (1.0f / 36.0f), 0.f);
        } else if (tid >= 256 && tid < 408) {
            const short hi = f2bf(ct_pf);
            const short lo = f2bf(ct_pf - bf2f(hi));
            xa_hi[cr][ck] = hi; xa_lo[cr][ck] = lo;           // data for step t+1
            if (ck >= 64) { xb_hi[cr][ck] = hi; xb_lo[cr][ck] = lo; }
            const int tn = (t + 2 < TT) ? t + 2 : TT - 1;
            ct_pf = packed[((size_t)(r0 + cr) * TT + tn) * DIN + ck];
        }
        BAR();

        // ---- P6: softmax+pi (shuffle) + SOM ring + L23 ring + output, wave=row ----
        if (tid < 256) {
            const int rr = w;   // 0..3
            float v = (lane < 48) ? preq[lane][rr] : -1e30f;
            if (lane < 36)       v += bqL[lane];
            else if (lane == 36) v += bpS;
            float sv = (lane < NN) ? v : -1e30f;
            #pragma unroll
            for (int d = 32; d >= 1; d >>= 1) sv = fmaxf(sv, __shfl_xor(sv, d));
            const float e_ = (lane < NN) ? expf(v - sv) : 0.f;
            float ss = e_;
            #pragma unroll
            for (int d = 32; d >= 1; d >>= 1) ss += __shfl_xor(ss, d);
            const float pi = sigm(__shfl(v, 36));
            if (lane < NN) {
                const int i = lane;
                const float dt = (e_ / ss) * pi;
                float acc = dt;
                #pragma unroll
                for (int j = 0; j < NN; j += 4) {
                    const float4 rv = *(const float4*)&soms[pp][rr][j];   // broadcast
                    const float4 wv = *(const float4*)&Wsom[i * NN + j];
                    acc += rv.x*wv.x + rv.y*wv.y + rv.z*wv.z + rv.w*wv.w;
                }
                const float sn = 0.9f * soms[pp][rr][i] + 0.1f * fmaxf(acc, 0.f);
                soms[qq][rr][i] = sn;

                float acc2 = (l4s[qq][rr][i] - dt) * (1.0f + 0.5f * dt) - 0.8f * sn - pvL[rr];
                #pragma unroll
                for (int j = 0; j < NN; j += 4) {
                    const float4 rv = *(const float4*)&l23s[pp][rr][j];   // broadcast
                    const float4 wv = *(const float4*)&Wl23[i * NN + j];
                    acc2 += rv.x*wv.x + rv.y*wv.y + rv.z*wv.z + rv.w*wv.w;
                }
                const float ln = 0.9f * l23s[pp][rr][i] + 0.1f * fmaxf(acc2, 0.f);
                l23s[qq][rr][i] = ln;
                const short hi = f2bf(ln);
                const short lo = f2bf(ln - bf2f(hi));
                xa_hi[rr][i] = hi; xa_lo[rr][i] = lo;          // x-part for t+1
                out[((size_t)(r0 + rr) * TT + t) * NN + i] = ln;
            }
        }
        BAR();
    }
}

extern "C" void kernel_launch(void* const* d_in, const int* in_sizes, int n_in,
                              void* d_out, int out_size, void* d_ws, size_t ws_size,
                              hipStream_t stream) {
    (void)in_sizes; (void)n_in; (void)out_size; (void)ws_size;
    const float* packed = (const float*)d_in[0];
    const float* Wl4    = (const float*)d_in[1];
    const float* Wl23   = (const float*)d_in[2];
    const float* Wsom   = (const float*)d_in[3];
    const float* Wz     = (const float*)d_in[4];
    const float* Wr     = (const float*)d_in[5];
    const float* Wh     = (const float*)d_in[6];
    const float* bz     = (const float*)d_in[7];
    const float* br     = (const float*)d_in[8];
    const float* bh     = (const float*)d_in[9];
    const float* Wq     = (const float*)d_in[10];
    const float* bq     = (const float*)d_in[11];
    const float* Wp     = (const float*)d_in[12];
    const float* bp     = (const float*)d_in[13];
    float* out  = (float*)d_out;
    short* frag = (short*)d_ws;   // needs 184320 B

    init_frags<<<(FRAG_TOTAL + 255) / 256, 256, 0, stream>>>(Wz, Wr, Wh, Wq, Wp, frag);
    laminar_kernel<<<256, 512, 0, stream>>>(packed, Wl4, Wl23, Wsom,
                                            bz, br, bh, bq, bp, frag, out);
}

// Round 4
// 2220.051 us; speedup vs baseline: 2.6346x; 1.0776x over previous
//
#include <hip/hip_runtime.h>
#include <cstdint>
#include <cstddef>

// LaminarV1V2Network: B=1024, T=512, N=36, H=128, D_in=74, K=202.
// R3: 4 barriers/step. P1: z,r MFMA + in-wave gate epilogue + L4 ring.
// P3: hh MFMA + fused h-update (tanh). P5: heads MFMA + PV + cue/task
// prefetch. P6: softmax + SOM/L23 rings + output. Native v_exp/v_rcp
// transcendentals. Branch-free A-frag reads (row = m&3, dup rows unread).
// 256 blocks x 512 threads, 4 rows/block, state in LDS.

#define NN   36
#define HH   128
#define DIN  74
#define KT   202
#define KP   224      // K padded to 7 slabs of 32
#define TT   512
#define RPB  4
#define NPAD 40

typedef short bf16x8 __attribute__((ext_vector_type(8)));
typedef float f32x4  __attribute__((ext_vector_type(4)));

#define MFMA(a,b,c) __builtin_amdgcn_mfma_f32_16x16x32_bf16((a),(b),(c),0,0,0)
// Barrier that orders LDS only: global loads/stores float across it.
#define BAR() asm volatile("s_waitcnt lgkmcnt(0)\n\ts_barrier" ::: "memory")

__device__ __forceinline__ float fastrcp(float x) { return __builtin_amdgcn_rcpf(x); }
__device__ __forceinline__ float sigmf(float x) {
    return fastrcp(1.0f + __expf(-x));
}
__device__ __forceinline__ float tanhf_fast(float x) {
    return 1.0f - 2.0f * fastrcp(1.0f + __expf(2.0f * x));
}

__device__ __forceinline__ short f2bf(float v) {
    union { float f; unsigned u; } x; x.f = v;
    unsigned r = (x.u + 0x7fffu + ((x.u >> 16) & 1u)) >> 16;   // RNE
    return (short)r;
}
__device__ __forceinline__ float bf2f(short s) {
    union { unsigned u; float f; } y; y.u = ((unsigned)(unsigned short)s) << 16;
    return y.f;
}

// ---- fragment layout in ws (shorts) ----
// GRU tiles T = m*8+nt (m: 0=Wz,1=Wr,2=Wh; nt: 16-feature tile), 7 slabs:
//   off = T*7*512 + s*512 + lane*8 + j ;  k = s*32 + (lane>>4)*8 + j, n = nt*16 + (lane&15)
// HEAD tiles t in [0,3), 4 slabs, base 86016:
//   off = 86016 + (t*4+s)*512 + lane*8 + j ; cols: <36 Wq, ==36 Wp, else 0
#define HEADBASE 86016
#define FRAG_TOTAL 92160

extern "C" __global__ void __launch_bounds__(256)
init_frags(const float* __restrict__ Wz, const float* __restrict__ Wr,
           const float* __restrict__ Wh, const float* __restrict__ Wq,
           const float* __restrict__ Wp, short* __restrict__ frag)
{
    int idx = blockIdx.x * 256 + threadIdx.x;
    if (idx >= FRAG_TOTAL) return;
    float v;
    if (idx < HEADBASE) {
        int T = idx / 3584; int rem = idx - T * 3584;
        int s = rem >> 9;   int e = rem & 511;
        int l = e >> 3, j = e & 7;
        int k = s * 32 + ((l >> 4) << 3) + j;
        int n = ((T & 7) << 4) + (l & 15);
        const float* W = (T < 8) ? Wz : (T < 16) ? Wr : Wh;
        v = (k < KT) ? W[k * HH + n] : 0.f;
    } else {
        int r2 = idx - HEADBASE;
        int ts = r2 >> 9; int e = r2 & 511;
        int t = ts >> 2, s = ts & 3;
        int l = e >> 3, j = e & 7;
        int k = s * 32 + ((l >> 4) << 3) + j;     // < 128
        int c = (t << 4) + (l & 15);
        v = (c < NN) ? Wq[k * NN + c] : (c == NN ? Wp[k] : 0.f);
    }
    frag[idx] = f2bf(v);
}

extern "C" __global__ void __launch_bounds__(512, 2)
laminar_kernel(const float* __restrict__ packed,
               const float* __restrict__ Wl4,
               const float* __restrict__ Wl23,
               const float* __restrict__ Wsom,
               const float* __restrict__ bz,
               const float* __restrict__ br,
               const float* __restrict__ bh,
               const float* __restrict__ bq,
               const float* __restrict__ bp,
               const short* __restrict__ frag,
               float* __restrict__ out)
{
    const int tid  = threadIdx.x;
    const int r0   = blockIdx.x * RPB;
    const int lane = tid & 63;
    const int w    = tid >> 6;
    const int m    = lane & 15;
    const int q    = lane >> 4;
    const int ma   = m & 3;          // A-operand row (rows 4-15 duplicate 0-3, unread)

    __shared__ __align__(16) short xa_hi[RPB][KP], xa_lo[RPB][KP];  // z/r A: [x, h]
    __shared__ __align__(16) short xb_hi[RPB][KP], xb_lo[RPB][KP];  // hh  A: [x, r*h]
    __shared__ __align__(16) short hb_hi[RPB][HH], hb_lo[RPB][HH];  // head A: h_new
    __shared__ float hS[HH][5];      // h state, [feature][row], stride-5
    __shared__ float zgS[HH][5];     // z gate,  [feature][row], stride-5
    __shared__ float preq[48][5];    // head pre-acts, [col][row], stride-5
    __shared__ __align__(16) float l4s[2][RPB][NPAD];
    __shared__ __align__(16) float l23s[2][RPB][NPAD];
    __shared__ __align__(16) float soms[2][RPB][NPAD];
    __shared__ __align__(16) float adL[RPB][NPAD];
    __shared__ float bzL[HH], brL[HH], bhL[HH], bqL[48];
    __shared__ float pvL[RPB];
    __shared__ float bpS;

    // ---- one-time init ----
    for (int i = tid; i < HH; i += 512) { bzL[i] = bz[i]; brL[i] = br[i]; bhL[i] = bh[i]; }
    for (int i = tid; i < 48; i += 512) bqL[i] = (i < NN) ? bq[i] : 0.f;
    if (tid == 0) bpS = bp[0];
    { short* p = (short*)xa_hi; for (int i = tid; i < RPB*KP; i += 512) p[i] = 0; }
    { short* p = (short*)xa_lo; for (int i = tid; i < RPB*KP; i += 512) p[i] = 0; }
    { short* p = (short*)xb_hi; for (int i = tid; i < RPB*KP; i += 512) p[i] = 0; }
    { short* p = (short*)xb_lo; for (int i = tid; i < RPB*KP; i += 512) p[i] = 0; }
    { short* p = (short*)hb_hi; for (int i = tid; i < RPB*HH; i += 512) p[i] = 0; }
    { short* p = (short*)hb_lo; for (int i = tid; i < RPB*HH; i += 512) p[i] = 0; }
    { float* p = (float*)hS;    for (int i = tid; i < HH*5;      i += 512) p[i] = 0.f; }
    { float* p = (float*)l4s;   for (int i = tid; i < 2*RPB*NPAD; i += 512) p[i] = 0.f; }
    { float* p = (float*)l23s;  for (int i = tid; i < 2*RPB*NPAD; i += 512) p[i] = 0.f; }
    { float* p = (float*)soms;  for (int i = tid; i < 2*RPB*NPAD; i += 512) p[i] = 0.f; }
    { float* p = (float*)adL;   for (int i = tid; i < RPB*NPAD;   i += 512) p[i] = 0.f; }
    if (tid < RPB) pvL[tid] = 0.f;

    // ---- persistent weight fragments in VGPRs ----
    const int g   = w >> 2;      // P1 gate (0=z waves 0-3, 1=r waves 4-7)
    const int nt0 = w & 3;       // P1 first tile (tiles nt0, nt0+4)
    bf16x8 Wg0[7], Wg1[7], WhR[7], WhdR[4];
    {
        const short* b0 = frag + ((g * 8 + nt0) * 7) * 512 + lane * 8;
        const short* b1 = frag + ((g * 8 + nt0 + 4) * 7) * 512 + lane * 8;
        #pragma unroll
        for (int s = 0; s < 7; ++s) {
            Wg0[s] = *(const bf16x8*)(b0 + s * 512);
            Wg1[s] = *(const bf16x8*)(b1 + s * 512);
        }
        const short* b2 = frag + ((16 + w) * 7) * 512 + lane * 8;
        #pragma unroll
        for (int s = 0; s < 7; ++s) WhR[s] = *(const bf16x8*)(b2 + s * 512);
        const int hw = (w < 3) ? w : 0;
        const short* b3 = frag + HEADBASE + (hw * 4) * 512 + lane * 8;
        #pragma unroll
        for (int s = 0; s < 4; ++s) WhdR[s] = *(const bf16x8*)(b3 + s * 512);
    }

    // ---- input prefetch prologue ----
    float stim_pf = 0.f; int sr = 0, si = 0;
    if (tid < 144) {
        sr = tid / NN; si = tid - sr * NN;
        stim_pf = packed[((size_t)(r0 + sr) * TT + 0) * DIN + si];
    }
    float ct_pf = 0.f; int cr = 0, ck = 0;
    if (tid >= 256 && tid < 408) {
        cr = (tid - 256) / 38; ck = 36 + (tid - 256) % 38;
        const float v0 = packed[((size_t)(r0 + cr) * TT + 0) * DIN + ck];
        const short hi = f2bf(v0);
        const short lo = f2bf(v0 - bf2f(hi));
        xa_hi[cr][ck] = hi; xa_lo[cr][ck] = lo;
        if (ck >= 64) { xb_hi[cr][ck] = hi; xb_lo[cr][ck] = lo; }
        ct_pf = packed[((size_t)(r0 + cr) * TT + 1) * DIN + ck];
    }
    __syncthreads();

    for (int t = 0; t < TT; ++t) {
        const int pp = t & 1;
        const int qq = 1 - pp;

        // ---- P1: z,r MFMA + in-wave gate epilogue + L4 ring ----
        bf16x8 Ahi[7], Alo[7];
        {
            #pragma unroll
            for (int s = 0; s < 7; ++s) {
                Ahi[s] = *(const bf16x8*)&xa_hi[ma][s * 32 + q * 8];
                Alo[s] = *(const bf16x8*)&xa_lo[ma][s * 32 + q * 8];
            }
            f32x4 acc0 = {0.f,0.f,0.f,0.f}, acc1 = {0.f,0.f,0.f,0.f};
            #pragma unroll
            for (int s = 0; s < 7; ++s) {
                acc0 = MFMA(Ahi[s], Wg0[s], acc0);
                acc1 = MFMA(Ahi[s], Wg1[s], acc1);
                acc0 = MFMA(Alo[s], Wg0[s], acc0);
                acc1 = MFMA(Alo[s], Wg1[s], acc1);
            }
            if (lane < 16) {
                const int fA = nt0 * 16 + lane;
                const int fB = fA + 64;
                if (g == 0) {                      // z-waves
                    #pragma unroll
                    for (int e = 0; e < 4; ++e) {
                        zgS[fA][e] = sigmf(acc0[e] + bzL[fA]);
                        zgS[fB][e] = sigmf(acc1[e] + bzL[fB]);
                    }
                } else {                           // r-waves: r*h -> xb bf16 hi/lo
                    #pragma unroll
                    for (int e = 0; e < 4; ++e) {
                        const float ra = sigmf(acc0[e] + brL[fA]) * hS[fA][e];
                        const float rb = sigmf(acc1[e] + brL[fB]) * hS[fB][e];
                        const short ha = f2bf(ra);
                        xb_hi[e][DIN + fA] = ha;
                        xb_lo[e][DIN + fA] = f2bf(ra - bf2f(ha));
                        const short hb = f2bf(rb);
                        xb_hi[e][DIN + fB] = hb;
                        xb_lo[e][DIN + fB] = f2bf(rb - bf2f(hb));
                    }
                }
            }
            if (tid < 144) {                       // L4 ring + adapt (z-waves)
                float acc = stim_pf - pvL[sr] - adL[sr][si];
                #pragma unroll
                for (int j = 0; j < NN; j += 4) {
                    const float4 rv = *(const float4*)&l4s[pp][sr][j];
                    const float4 wv = *(const float4*)&Wl4[si * NN + j];
                    acc += rv.x*wv.x + rv.y*wv.y + rv.z*wv.z + rv.w*wv.w;
                }
                const float nl4 = 0.9f * l4s[pp][sr][si] + 0.1f * fmaxf(acc, 0.f);
                l4s[qq][sr][si] = nl4;
                adL[sr][si] = 0.98f * adL[sr][si] + 0.01f * nl4;
                const int tn = (t + 1 < TT) ? t + 1 : t;
                stim_pf = packed[((size_t)(r0 + sr) * TT + tn) * DIN + si];
            }
        }
        BAR();

        // ---- P3: hh MFMA + fused h update (tanh) ----
        {
            bf16x8 Bhi[5], Blo[5];
            #pragma unroll
            for (int s = 0; s < 5; ++s) {
                Bhi[s] = *(const bf16x8*)&xb_hi[ma][(s + 2) * 32 + q * 8];
                Blo[s] = *(const bf16x8*)&xb_lo[ma][(s + 2) * 32 + q * 8];
            }
            f32x4 ah = {0.f,0.f,0.f,0.f}, al = {0.f,0.f,0.f,0.f};
            #pragma unroll
            for (int s = 0; s < 2; ++s) {
                ah = MFMA(Ahi[s], WhR[s], ah);
                al = MFMA(Alo[s], WhR[s], al);
            }
            #pragma unroll
            for (int s = 2; s < 7; ++s) {
                ah = MFMA(Bhi[s - 2], WhR[s], ah);
                al = MFMA(Blo[s - 2], WhR[s], al);
            }
            if (lane < 16) {
                const int f = (w << 4) + lane;     // 0..127
                #pragma unroll
                for (int e = 0; e < 4; ++e) {
                    const float hhv = tanhf_fast(ah[e] + al[e] + bhL[f]);
                    const float zg  = zgS[f][e];
                    const float hn  = (1.0f - zg) * hS[f][e] + zg * hhv;
                    hS[f][e] = hn;
                    const short hi = f2bf(hn);
                    const short lo = f2bf(hn - bf2f(hi));
                    hb_hi[e][f] = hi;       hb_lo[e][f] = lo;
                    xa_hi[e][DIN + f] = hi; xa_lo[e][DIN + f] = lo;
                }
            }
        }
        BAR();

        // ---- P5: heads MFMA (w<3) | PV (w==3) | cue/task store+prefetch ----
        if (w < 3) {
            bf16x8 Hhi[4], Hlo[4];
            #pragma unroll
            for (int s = 0; s < 4; ++s) {
                Hhi[s] = *(const bf16x8*)&hb_hi[ma][s * 32 + q * 8];
                Hlo[s] = *(const bf16x8*)&hb_lo[ma][s * 32 + q * 8];
            }
            f32x4 ah = {0.f,0.f,0.f,0.f}, al = {0.f,0.f,0.f,0.f};
            #pragma unroll
            for (int s = 0; s < 4; ++s) {
                ah = MFMA(Hhi[s], WhdR[s], ah);
                al = MFMA(Hlo[s], WhdR[s], al);
            }
            if (lane < 16) {
                #pragma unroll
                for (int e = 0; e < 4; ++e) preq[w * 16 + lane][e] = ah[e] + al[e];
            }
        } else if (w == 3) {
            const int row = lane >> 4;
            const int jj  = lane & 15;
            float s = 0.f;
            for (int j = jj; j < NN; j += 16) s += l4s[qq][row][j] + l23s[pp][row][j];
            s += __shfl_xor(s, 8); s += __shfl_xor(s, 4);
            s += __shfl_xor(s, 2); s += __shfl_xor(s, 1);
            if (jj == 0) pvL[row] = 0.9f * pvL[row] + 0.1f * fmaxf(s * (1.0f / 36.0f), 0.f);
        } else if (tid >= 256 && tid < 408) {
            const short hi = f2bf(ct_pf);
            const short lo = f2bf(ct_pf - bf2f(hi));
            xa_hi[cr][ck] = hi; xa_lo[cr][ck] = lo;           // data for step t+1
            if (ck >= 64) { xb_hi[cr][ck] = hi; xb_lo[cr][ck] = lo; }
            const int tn = (t + 2 < TT) ? t + 2 : TT - 1;
            ct_pf = packed[((size_t)(r0 + cr) * TT + tn) * DIN + ck];
        }
        BAR();

        // ---- P6: softmax+pi (shuffle) + SOM ring + L23 ring + output, wave=row ----
        if (tid < 256) {
            const int rr = w;   // 0..3
            float v = (lane < 48) ? preq[lane][rr] : -1e30f;
            if (lane < 36)       v += bqL[lane];
            else if (lane == 36) v += bpS;
            float sv = (lane < NN) ? v : -1e30f;
            #pragma unroll
            for (int d = 32; d >= 1; d >>= 1) sv = fmaxf(sv, __shfl_xor(sv, d));
            const float e_ = (lane < NN) ? __expf(v - sv) : 0.f;
            float ss = e_;
            #pragma unroll
            for (int d = 32; d >= 1; d >>= 1) ss += __shfl_xor(ss, d);
            const float pi = sigmf(__shfl(v, 36));
            if (lane < NN) {
                const int i = lane;
                const float dt = e_ * fastrcp(ss) * pi;
                float acc = dt;
                #pragma unroll
                for (int j = 0; j < NN; j += 4) {
                    const float4 rv = *(const float4*)&soms[pp][rr][j];   // broadcast
                    const float4 wv = *(const float4*)&Wsom[i * NN + j];
                    acc += rv.x*wv.x + rv.y*wv.y + rv.z*wv.z + rv.w*wv.w;
                }
                const float sn = 0.9f * soms[pp][rr][i] + 0.1f * fmaxf(acc, 0.f);
                soms[qq][rr][i] = sn;

                float acc2 = (l4s[qq][rr][i] - dt) * (1.0f + 0.5f * dt) - 0.8f * sn - pvL[rr];
                #pragma unroll
                for (int j = 0; j < NN; j += 4) {
                    const float4 rv = *(const float4*)&l23s[pp][rr][j];   // broadcast
                    const float4 wv = *(const float4*)&Wl23[i * NN + j];
                    acc2 += rv.x*wv.x + rv.y*wv.y + rv.z*wv.z + rv.w*wv.w;
                }
                const float ln = 0.9f * l23s[pp][rr][i] + 0.1f * fmaxf(acc2, 0.f);
                l23s[qq][rr][i] = ln;
                const short hi = f2bf(ln);
                const short lo = f2bf(ln - bf2f(hi));
                xa_hi[rr][i] = hi; xa_lo[rr][i] = lo;          // x-part for t+1
                out[((size_t)(r0 + rr) * TT + t) * NN + i] = ln;
            }
        }
        BAR();
    }
}

extern "C" void kernel_launch(void* const* d_in, const int* in_sizes, int n_in,
                              void* d_out, int out_size, void* d_ws, size_t ws_size,
                              hipStream_t stream) {
    (void)in_sizes; (void)n_in; (void)out_size; (void)ws_size;
    const float* packed = (const float*)d_in[0];
    const float* Wl4    = (const float*)d_in[1];
    const float* Wl23   = (const float*)d_in[2];
    const float* Wsom   = (const float*)d_in[3];
    const float* Wz     = (const float*)d_in[4];
    const float* Wr     = (const float*)d_in[5];
    const float* Wh     = (const float*)d_in[6];
    const float* bz     = (const float*)d_in[7];
    const float* br     = (const float*)d_in[8];
    const float* bh     = (const float*)d_in[9];
    const float* Wq     = (const float*)d_in[10];
    const float* bq     = (const float*)d_in[11];
    const float* Wp     = (const float*)d_in[12];
    const float* bp     = (const float*)d_in[13];
    float* out  = (float*)d_out;
    short* frag = (short*)d_ws;   // needs 184320 B

    init_frags<<<(FRAG_TOTAL + 255) / 256, 256, 0, stream>>>(Wz, Wr, Wh, Wq, Wp, frag);
    laminar_kernel<<<256, 512, 0, stream>>>(packed, Wl4, Wl23, Wsom,
                                            bz, br, bh, bq, bp, frag, out);
}

// Round 5
// 2178.291 us; speedup vs baseline: 2.6851x; 1.0192x over previous
//
#include <hip/hip_runtime.h>
#include <cstdint>
#include <cstddef>

// LaminarV1V2Network: B=1024, T=512, N=36, H=128, D_in=74, K=202.
// R4: hi/lo packed into A rows 0-3/4-7 of ONE MFMA (combine via shfl_xor 16)
// => MFMA count halved. Ring dot-products hoisted off the critical path:
// l23dot/somdot in P1 (from t-1 state), l4 dot in P5 (for t+1), P6 is just
// softmax + pointwise. Ring weights in LDS. Single-buffered state.
// 4 lgkm-only barriers/step. 256 blocks x 512 threads, 4 rows/block.

#define NN   36
#define HH   128
#define DIN  74
#define KT   202
#define KP   224      // K padded to 7 slabs of 32
#define TT   512
#define RPB  4
#define NPAD 40
#define WSTR 44       // LDS ring-weight row stride (floats)

typedef short bf16x8 __attribute__((ext_vector_type(8)));
typedef float f32x4  __attribute__((ext_vector_type(4)));

#define MFMA(a,b,c) __builtin_amdgcn_mfma_f32_16x16x32_bf16((a),(b),(c),0,0,0)
// Barrier that orders LDS only: global loads/stores float across it.
#define BAR() asm volatile("s_waitcnt lgkmcnt(0)\n\ts_barrier" ::: "memory")

__device__ __forceinline__ float fastrcp(float x) { return __builtin_amdgcn_rcpf(x); }
__device__ __forceinline__ float sigmf(float x) { return fastrcp(1.0f + __expf(-x)); }
__device__ __forceinline__ float tanhf_fast(float x) {
    return 1.0f - 2.0f * fastrcp(1.0f + __expf(2.0f * x));
}

__device__ __forceinline__ short f2bf(float v) {
    union { float f; unsigned u; } x; x.f = v;
    unsigned r = (x.u + 0x7fffu + ((x.u >> 16) & 1u)) >> 16;   // RNE
    return (short)r;
}
__device__ __forceinline__ float bf2f(short s) {
    union { unsigned u; float f; } y; y.u = ((unsigned)(unsigned short)s) << 16;
    return y.f;
}

// ---- fragment layout in ws (shorts) ----
// GRU tiles T = m*8+nt (m: 0=Wz,1=Wr,2=Wh; nt: 16-feature tile), 7 slabs:
//   off = T*7*512 + s*512 + lane*8 + j ;  k = s*32 + (lane>>4)*8 + j, n = nt*16 + (lane&15)
// HEAD tiles t in [0,3), 4 slabs, base 86016:
//   off = 86016 + (t*4+s)*512 + lane*8 + j ; cols: <36 Wq, ==36 Wp, else 0
#define HEADBASE 86016
#define FRAG_TOTAL 92160

extern "C" __global__ void __launch_bounds__(256)
init_frags(const float* __restrict__ Wz, const float* __restrict__ Wr,
           const float* __restrict__ Wh, const float* __restrict__ Wq,
           const float* __restrict__ Wp, short* __restrict__ frag)
{
    int idx = blockIdx.x * 256 + threadIdx.x;
    if (idx >= FRAG_TOTAL) return;
    float v;
    if (idx < HEADBASE) {
        int T = idx / 3584; int rem = idx - T * 3584;
        int s = rem >> 9;   int e = rem & 511;
        int l = e >> 3, j = e & 7;
        int k = s * 32 + ((l >> 4) << 3) + j;
        int n = ((T & 7) << 4) + (l & 15);
        const float* W = (T < 8) ? Wz : (T < 16) ? Wr : Wh;
        v = (k < KT) ? W[k * HH + n] : 0.f;
    } else {
        int r2 = idx - HEADBASE;
        int ts = r2 >> 9; int e = r2 & 511;
        int t = ts >> 2, s = ts & 3;
        int l = e >> 3, j = e & 7;
        int k = s * 32 + ((l >> 4) << 3) + j;     // < 128
        int c = (t << 4) + (l & 15);
        v = (c < NN) ? Wq[k * NN + c] : (c == NN ? Wp[k] : 0.f);
    }
    frag[idx] = f2bf(v);
}

extern "C" __global__ void __launch_bounds__(512, 2)
laminar_kernel(const float* __restrict__ packed,
               const float* __restrict__ Wl4,
               const float* __restrict__ Wl23,
               const float* __restrict__ Wsom,
               const float* __restrict__ bz,
               const float* __restrict__ br,
               const float* __restrict__ bh,
               const float* __restrict__ bq,
               const float* __restrict__ bp,
               const short* __restrict__ frag,
               float* __restrict__ out)
{
    const int tid  = threadIdx.x;
    const int r0   = blockIdx.x * RPB;
    const int lane = tid & 63;
    const int w    = tid >> 6;
    const int m    = lane & 15;
    const int q    = lane >> 4;
    const int ma   = m & 3;              // batch row within A tile
    const int sel  = (m >> 2) & 1;       // 0: hi operand rows, 1: lo operand rows

    __shared__ __align__(16) short xa_hi[RPB][KP], xa_lo[RPB][KP];  // z/r A: [x, h]
    __shared__ __align__(16) short xb_hi[RPB][KP], xb_lo[RPB][KP];  // hh  A: [x, r*h]
    __shared__ __align__(16) short hb_hi[RPB][HH], hb_lo[RPB][HH];  // head A: h_new
    __shared__ float hS[HH][5];      // h state, [feature][row], stride-5
    __shared__ float zgS[HH][5];     // z gate
    __shared__ float preq[48][5];    // head pre-acts, [col][row]
    __shared__ __align__(16) float Wl4S[NN * WSTR], Wl23S[NN * WSTR], WsomS[NN * WSTR];
    __shared__ __align__(16) float l4s[RPB][NPAD], l23s[RPB][NPAD];
    __shared__ __align__(16) float soms[RPB][NPAD], adL[RPB][NPAD];
    __shared__ __align__(16) float l4part[RPB][NPAD];   // stim(t)+Wl4*l4(t-1)-adapt(t-1)
    __shared__ __align__(16) float l23dotS[RPB][NPAD];  // Wl23*l23(t-1)
    __shared__ __align__(16) float somdotS[RPB][NPAD];  // Wsom*som(t-1)
    __shared__ float bzL[HH], brL[HH], bhL[HH], bqL[48];
    __shared__ float pvL[RPB];
    __shared__ float bpS;

    // ---- one-time init ----
    for (int i = tid; i < HH; i += 512) { bzL[i] = bz[i]; brL[i] = br[i]; bhL[i] = bh[i]; }
    for (int i = tid; i < 48; i += 512) bqL[i] = (i < NN) ? bq[i] : 0.f;
    if (tid == 0) bpS = bp[0];
    for (int idx = tid; idx < NN * NN; idx += 512) {
        const int i = idx / NN, j = idx - i * NN;
        Wl4S[i * WSTR + j]  = Wl4[idx];
        Wl23S[i * WSTR + j] = Wl23[idx];
        WsomS[i * WSTR + j] = Wsom[idx];
    }
    { short* p = (short*)xa_hi; for (int i = tid; i < RPB*KP; i += 512) p[i] = 0; }
    { short* p = (short*)xa_lo; for (int i = tid; i < RPB*KP; i += 512) p[i] = 0; }
    { short* p = (short*)xb_hi; for (int i = tid; i < RPB*KP; i += 512) p[i] = 0; }
    { short* p = (short*)xb_lo; for (int i = tid; i < RPB*KP; i += 512) p[i] = 0; }
    { float* p = (float*)hS;    for (int i = tid; i < HH*5;    i += 512) p[i] = 0.f; }
    { float* p = (float*)l4s;   for (int i = tid; i < RPB*NPAD; i += 512) {
        p[i] = 0.f; ((float*)l23s)[i] = 0.f; ((float*)soms)[i] = 0.f;
        ((float*)adL)[i] = 0.f; ((float*)l23dotS)[i] = 0.f; ((float*)somdotS)[i] = 0.f; } }
    if (tid < RPB) pvL[tid] = 0.f;
    // l4part(0) = stim(0) (all state zero)
    if (tid < 144) {
        const int r = tid / NN, i = tid - (tid / NN) * NN;
        l4part[r][i] = packed[((size_t)(r0 + r) * TT + 0) * DIN + i];
    }

    // ---- persistent weight fragments in VGPRs ----
    const int g   = w >> 2;      // P1 gate (0=z waves 0-3, 1=r waves 4-7)
    const int nt0 = w & 3;       // P1 tiles nt0, nt0+4
    bf16x8 Wg0[7], Wg1[7], WhR[7], WhdR[4];
    {
        const short* b0 = frag + ((g * 8 + nt0) * 7) * 512 + lane * 8;
        const short* b1 = frag + ((g * 8 + nt0 + 4) * 7) * 512 + lane * 8;
        #pragma unroll
        for (int s = 0; s < 7; ++s) {
            Wg0[s] = *(const bf16x8*)(b0 + s * 512);
            Wg1[s] = *(const bf16x8*)(b1 + s * 512);
        }
        const short* b2 = frag + ((16 + w) * 7) * 512 + lane * 8;
        #pragma unroll
        for (int s = 0; s < 7; ++s) WhR[s] = *(const bf16x8*)(b2 + s * 512);
        const int hw = (w < 3) ? w : 0;
        const short* b3 = frag + HEADBASE + (hw * 4) * 512 + lane * 8;
        #pragma unroll
        for (int s = 0; s < 4; ++s) WhdR[s] = *(const bf16x8*)(b3 + s * 512);
    }

    // ---- cue/task prologue: stage t=0, prefetch t=1 (2 cols/thread) ----
    float ctv0 = 0.f, ctv1 = 0.f; int ctr = 0, ctc = 0;
    if (tid >= 400 && tid < 476) {
        const int u = tid - 400; ctr = u / 19; ctc = 36 + 2 * (u - ctr * 19);
        const size_t base0 = ((size_t)(r0 + ctr) * TT + 0) * DIN;
        #pragma unroll
        for (int d = 0; d < 2; ++d) {
            const float v = packed[base0 + ctc + d];
            const short hi = f2bf(v), lo = f2bf(v - bf2f(hi));
            xa_hi[ctr][ctc + d] = hi; xa_lo[ctr][ctc + d] = lo;
            if (ctc + d >= 64) { xb_hi[ctr][ctc + d] = hi; xb_lo[ctr][ctc + d] = lo; }
        }
        const size_t base1 = ((size_t)(r0 + ctr) * TT + 1) * DIN;
        ctv0 = packed[base1 + ctc]; ctv1 = packed[base1 + ctc + 1];
    }
    // stim prefetch regs (used by P5's l4 dot)
    float stimreg = 0.f; int sr = 0, si = 0;
    if (tid >= 256 && tid < 400) { const int u = tid - 256; sr = u / NN; si = u - sr * NN; }
    __syncthreads();

    for (int t = 0; t < TT; ++t) {
        // ---- P1: z,r MFMA (hi/lo packed rows) + gate epilogue
        //          + l4 finalize + l23dot + somdot + stim prefetch ----
        bf16x8 Apk[7];
        {
            const short* xaP = sel ? &xa_lo[ma][0] : &xa_hi[ma][0];
            #pragma unroll
            for (int s = 0; s < 7; ++s)
                Apk[s] = *(const bf16x8*)&xaP[s * 32 + q * 8];
            f32x4 a0 = {0.f,0.f,0.f,0.f}, a1 = {0.f,0.f,0.f,0.f};
            #pragma unroll
            for (int s = 0; s < 7; ++s) {
                a0 = MFMA(Apk[s], Wg0[s], a0);
                a1 = MFMA(Apk[s], Wg1[s], a1);
            }
            #pragma unroll
            for (int e = 0; e < 4; ++e) {       // hi rows (0-3) + lo rows (4-7)
                a0[e] += __shfl_xor(a0[e], 16);
                a1[e] += __shfl_xor(a1[e], 16);
            }
            if (lane < 16) {
                const int fA = nt0 * 16 + lane;
                const int fB = fA + 64;
                if (g == 0) {
                    #pragma unroll
                    for (int e = 0; e < 4; ++e) {
                        zgS[fA][e] = sigmf(a0[e] + bzL[fA]);
                        zgS[fB][e] = sigmf(a1[e] + bzL[fB]);
                    }
                } else {
                    #pragma unroll
                    for (int e = 0; e < 4; ++e) {
                        const float ra = sigmf(a0[e] + brL[fA]) * hS[fA][e];
                        const float rb = sigmf(a1[e] + brL[fB]) * hS[fB][e];
                        const short ha = f2bf(ra);
                        xb_hi[e][DIN + fA] = ha;
                        xb_lo[e][DIN + fA] = f2bf(ra - bf2f(ha));
                        const short hb = f2bf(rb);
                        xb_hi[e][DIN + fB] = hb;
                        xb_lo[e][DIN + fB] = f2bf(rb - bf2f(hb));
                    }
                }
            }
        }
        if (tid < 144) {                       // l4(t) finalize from l4part(t), pv(t-1)
            const int r = tid / NN, i = tid - (tid / NN) * NN;
            const float nl4 = 0.9f * l4s[r][i] + 0.1f * fmaxf(l4part[r][i] - pvL[r], 0.f);
            l4s[r][i] = nl4;
            adL[r][i] = 0.98f * adL[r][i] + 0.01f * nl4;
        } else if (tid < 288) {                // l23dot(t) from l23(t-1)
            const int u = tid - 144;
            const int r = u / NN, i = u - (u / NN) * NN;
            float acc = 0.f;
            #pragma unroll
            for (int j = 0; j < NN; j += 4) {
                const float4 sv = *(const float4*)&l23s[r][j];
                const float4 wv = *(const float4*)&Wl23S[i * WSTR + j];
                acc += sv.x*wv.x + sv.y*wv.y + sv.z*wv.z + sv.w*wv.w;
            }
            l23dotS[r][i] = acc;
        } else if (tid < 432) {                // somdot(t) from som(t-1)
            const int u = tid - 288;
            const int r = u / NN, i = u - (u / NN) * NN;
            float acc = 0.f;
            #pragma unroll
            for (int j = 0; j < NN; j += 4) {
                const float4 sv = *(const float4*)&soms[r][j];
                const float4 wv = *(const float4*)&WsomS[i * WSTR + j];
                acc += sv.x*wv.x + sv.y*wv.y + sv.z*wv.z + sv.w*wv.w;
            }
            somdotS[r][i] = acc;
        }
        if (tid >= 256 && tid < 400) {         // stim(t+1) for P5's l4part(t+1)
            const int tn = (t + 1 < TT) ? t + 1 : t;
            stimreg = packed[((size_t)(r0 + sr) * TT + tn) * DIN + si];
        }
        BAR();

        // ---- P3: hh MFMA + fused h update ----
        {
            const short* xbP = sel ? &xb_lo[ma][0] : &xb_hi[ma][0];
            bf16x8 Bpk[5];
            #pragma unroll
            for (int s = 0; s < 5; ++s)
                Bpk[s] = *(const bf16x8*)&xbP[(s + 2) * 32 + q * 8];
            f32x4 a = {0.f,0.f,0.f,0.f};
            a = MFMA(Apk[0], WhR[0], a);
            a = MFMA(Apk[1], WhR[1], a);
            #pragma unroll
            for (int s = 2; s < 7; ++s) a = MFMA(Bpk[s - 2], WhR[s], a);
            #pragma unroll
            for (int e = 0; e < 4; ++e) a[e] += __shfl_xor(a[e], 16);
            if (lane < 16) {
                const int f = (w << 4) + lane;     // 0..127
                #pragma unroll
                for (int e = 0; e < 4; ++e) {
                    const float hhv = tanhf_fast(a[e] + bhL[f]);
                    const float zg  = zgS[f][e];
                    const float hn  = (1.0f - zg) * hS[f][e] + zg * hhv;
                    hS[f][e] = hn;
                    const short hi = f2bf(hn);
                    const short lo = f2bf(hn - bf2f(hi));
                    hb_hi[e][f] = hi;       hb_lo[e][f] = lo;
                    xa_hi[e][DIN + f] = hi; xa_lo[e][DIN + f] = lo;
                }
            }
        }
        BAR();

        // ---- P5: heads MFMA (w<3) | PV (w==3) | l4part(t+1) | cue/task(t+1) ----
        if (w < 3) {
            const short* hbP = sel ? &hb_lo[ma][0] : &hb_hi[ma][0];
            bf16x8 Hk[4];
            #pragma unroll
            for (int s = 0; s < 4; ++s)
                Hk[s] = *(const bf16x8*)&hbP[s * 32 + q * 8];
            f32x4 a = {0.f,0.f,0.f,0.f};
            #pragma unroll
            for (int s = 0; s < 4; ++s) a = MFMA(Hk[s], WhdR[s], a);
            #pragma unroll
            for (int e = 0; e < 4; ++e) a[e] += __shfl_xor(a[e], 16);
            if (lane < 16) {
                #pragma unroll
                for (int e = 0; e < 4; ++e) preq[w * 16 + lane][e] = a[e];
            }
        } else if (w == 3) {                   // PV: l4(t) + l23(t-1)
            const int row = lane >> 4;
            const int jj  = lane & 15;
            float s = 0.f;
            for (int j = jj; j < NN; j += 16) s += l4s[row][j] + l23s[row][j];
            s += __shfl_xor(s, 8); s += __shfl_xor(s, 4);
            s += __shfl_xor(s, 2); s += __shfl_xor(s, 1);
            if (jj == 0) pvL[row] = 0.9f * pvL[row] + 0.1f * fmaxf(s * (1.0f / 36.0f), 0.f);
        }
        if (tid >= 256 && tid < 400) {         // l4part(t+1) = stim(t+1)+Wl4*l4(t)-adapt(t)
            float acc = stimreg - adL[sr][si];
            #pragma unroll
            for (int j = 0; j < NN; j += 4) {
                const float4 sv = *(const float4*)&l4s[sr][j];
                const float4 wv = *(const float4*)&Wl4S[si * WSTR + j];
                acc += sv.x*wv.x + sv.y*wv.y + sv.z*wv.z + sv.w*wv.w;
            }
            l4part[sr][si] = acc;
        } else if (tid >= 400 && tid < 476) {  // cue/task(t+1) -> LDS; prefetch t+2
            #pragma unroll
            for (int d = 0; d < 2; ++d) {
                const float v = d ? ctv1 : ctv0;
                const short hi = f2bf(v), lo = f2bf(v - bf2f(hi));
                xa_hi[ctr][ctc + d] = hi; xa_lo[ctr][ctc + d] = lo;
                if (ctc + d >= 64) { xb_hi[ctr][ctc + d] = hi; xb_lo[ctr][ctc + d] = lo; }
            }
            const int tn = (t + 2 < TT) ? t + 2 : TT - 1;
            const size_t base = ((size_t)(r0 + ctr) * TT + tn) * DIN;
            ctv0 = packed[base + ctc]; ctv1 = packed[base + ctc + 1];
        }
        BAR();

        // ---- P6: softmax+pi + pointwise SOM/L23 updates + output, wave=row ----
        if (tid < 256) {
            const int rr = w;   // 0..3
            float v = (lane < 48) ? preq[lane][rr] : -1e30f;
            if (lane < 36)       v += bqL[lane];
            else if (lane == 36) v += bpS;
            float sv = (lane < NN) ? v : -1e30f;
            #pragma unroll
            for (int d = 32; d >= 1; d >>= 1) sv = fmaxf(sv, __shfl_xor(sv, d));
            const float e_ = (lane < NN) ? __expf(v - sv) : 0.f;
            float ss = e_;
            #pragma unroll
            for (int d = 32; d >= 1; d >>= 1) ss += __shfl_xor(ss, d);
            const float pi = sigmf(__shfl(v, 36));
            if (lane < NN) {
                const int i = lane;
                const float dt = e_ * fastrcp(ss) * pi;
                const float sn = 0.9f * soms[rr][i]
                               + 0.1f * fmaxf(dt + somdotS[rr][i], 0.f);
                soms[rr][i] = sn;
                const float acc2 = (l4s[rr][i] - dt) * (1.0f + 0.5f * dt)
                                 + l23dotS[rr][i] - 0.8f * sn - pvL[rr];
                const float ln = 0.9f * l23s[rr][i] + 0.1f * fmaxf(acc2, 0.f);
                l23s[rr][i] = ln;
                const short hi = f2bf(ln);
                xa_hi[rr][i] = hi; xa_lo[rr][i] = f2bf(ln - bf2f(hi));
                out[((size_t)(r0 + rr) * TT + t) * NN + i] = ln;
            }
        }
        BAR();
    }
}

extern "C" void kernel_launch(void* const* d_in, const int* in_sizes, int n_in,
                              void* d_out, int out_size, void* d_ws, size_t ws_size,
                              hipStream_t stream) {
    (void)in_sizes; (void)n_in; (void)out_size; (void)ws_size;
    const float* packed = (const float*)d_in[0];
    const float* Wl4    = (const float*)d_in[1];
    const float* Wl23   = (const float*)d_in[2];
    const float* Wsom   = (const float*)d_in[3];
    const float* Wz     = (const float*)d_in[4];
    const float* Wr     = (const float*)d_in[5];
    const float* Wh     = (const float*)d_in[6];
    const float* bz     = (const float*)d_in[7];
    const float* br     = (const float*)d_in[8];
    const float* bh     = (const float*)d_in[9];
    const float* Wq     = (const float*)d_in[10];
    const float* bq     = (const float*)d_in[11];
    const float* Wp     = (const float*)d_in[12];
    const float* bp     = (const float*)d_in[13];
    float* out  = (float*)d_out;
    short* frag = (short*)d_ws;   // needs 184320 B

    init_frags<<<(FRAG_TOTAL + 255) / 256, 256, 0, stream>>>(Wz, Wr, Wh, Wq, Wp, frag);
    laminar_kernel<<<256, 512, 0, stream>>>(packed, Wl4, Wl23, Wsom,
                                            bz, br, bh, bq, bp, frag, out);
}